// Round 2
// baseline (145.901 us; speedup 1.0000x reference)
//
#include <hip/hip_runtime.h>

#define NROWS 5
#define NB 13          // output bases per row: 17 knots - 1 - k(=3)

typedef float f32x4 __attribute__((ext_vector_type(4)));

// knot i value (uniform extended grid): g[i] = 0.2*i - 1.6
__device__ __forceinline__ float knot(int i) { return 0.2f * (float)i - 1.6f; }

template <int VEC>
__global__ __launch_bounds__(256) void bspline_kernel(const float* __restrict__ x,
                                                      float* __restrict__ out,
                                                      int cols, int nvec) {
    int tid = blockIdx.x * blockDim.x + threadIdx.x;
    int total = NROWS * nvec;
    if (tid >= total) return;
    int row = tid / nvec;
    int v = tid - row * nvec;
    size_t col = (size_t)v * VEC;

    float xs[VEC];
    if constexpr (VEC == 4) {
        const f32x4 xv = __builtin_nontemporal_load(
            reinterpret_cast<const f32x4*>(x + (size_t)row * cols + col));
        xs[0] = xv.x; xs[1] = xv.y; xs[2] = xv.z; xs[3] = xv.w;
    } else {
        xs[0] = x[(size_t)row * cols + col];
    }

    float res[VEC][NB];
    #pragma unroll
    for (int q = 0; q < VEC; ++q) {
        const float xx = xs[q];

        // degree 0: indicator of [g[i], g[i+1])
        float B0[16];
        #pragma unroll
        for (int i = 0; i < 16; ++i) {
            B0[i] = (xx >= knot(i) && xx < knot(i + 1)) ? 1.0f : 0.0f;
        }

        // degree 1: denom = 0.2 -> inv 5
        float B1[15];
        #pragma unroll
        for (int i = 0; i < 15; ++i) {
            B1[i] = (xx - knot(i)) * 5.0f * B0[i] + (knot(i + 2) - xx) * 5.0f * B0[i + 1];
        }

        // degree 2: denom = 0.4 -> inv 2.5
        float B2[14];
        #pragma unroll
        for (int i = 0; i < 14; ++i) {
            B2[i] = (xx - knot(i)) * 2.5f * B1[i] + (knot(i + 3) - xx) * 2.5f * B1[i + 1];
        }

        // degree 3: denom = 0.6 -> inv 5/3
        #pragma unroll
        for (int i = 0; i < NB; ++i) {
            res[q][i] = (xx - knot(i)) * (5.0f / 3.0f) * B2[i] +
                        (knot(i + 4) - xx) * (5.0f / 3.0f) * B2[i + 1];
        }
    }

    #pragma unroll
    for (int b = 0; b < NB; ++b) {
        size_t off = ((size_t)row * NB + b) * cols + col;
        if constexpr (VEC == 4) {
            f32x4 o;
            o.x = res[0][b]; o.y = res[1][b]; o.z = res[2][b]; o.w = res[3][b];
            __builtin_nontemporal_store(o, reinterpret_cast<f32x4*>(out + off));
        } else {
            out[off] = res[0][b];
        }
    }
}

extern "C" void kernel_launch(void* const* d_in, const int* in_sizes, int n_in,
                              void* d_out, int out_size, void* d_ws, size_t ws_size,
                              hipStream_t stream) {
    const float* x = (const float*)d_in[0];
    float* out = (float*)d_out;
    int cols = in_sizes[0] / NROWS;

    if ((cols & 3) == 0) {
        int nvec = cols / 4;
        int total = NROWS * nvec;
        int blocks = (total + 255) / 256;
        bspline_kernel<4><<<blocks, 256, 0, stream>>>(x, out, cols, nvec);
    } else {
        int total = NROWS * cols;
        int blocks = (total + 255) / 256;
        bspline_kernel<1><<<blocks, 256, 0, stream>>>(x, out, cols, cols);
    }
}

// Round 3
// 140.696 us; speedup vs baseline: 1.0370x; 1.0370x over previous
//
#include <hip/hip_runtime.h>

#define NROWS 5
#define NB 13          // output bases per row: 17 knots - 1 - k(=3)

typedef float f32x4 __attribute__((ext_vector_type(4)));

// knot i value (uniform extended grid): g[i] = 0.2*i - 1.6
__device__ __forceinline__ float knot(int i) { return 0.2f * (float)i - 1.6f; }

template <int VEC>
__global__ __launch_bounds__(256) void bspline_kernel(const float* __restrict__ x,
                                                      float* __restrict__ out,
                                                      int cols, int nvec) {
    int tid = blockIdx.x * blockDim.x + threadIdx.x;
    int total = NROWS * nvec;
    if (tid >= total) return;
    int row = tid / nvec;
    int v = tid - row * nvec;
    size_t col = (size_t)v * VEC;

    float xs[VEC];
    if constexpr (VEC == 4) {
        const f32x4 xv = __builtin_nontemporal_load(
            reinterpret_cast<const f32x4*>(x + (size_t)row * cols + col));
        xs[0] = xv.x; xs[1] = xv.y; xs[2] = xv.z; xs[3] = xv.w;
    } else {
        xs[0] = x[(size_t)row * cols + col];
    }

    float res[VEC][NB];
    #pragma unroll
    for (int q = 0; q < VEC; ++q) {
        const float xx = xs[q];

        // degree 0: indicator of [g[i], g[i+1])
        float B0[16];
        #pragma unroll
        for (int i = 0; i < 16; ++i) {
            B0[i] = (xx >= knot(i) && xx < knot(i + 1)) ? 1.0f : 0.0f;
        }

        // degree 1: denom = 0.2 -> inv 5
        float B1[15];
        #pragma unroll
        for (int i = 0; i < 15; ++i) {
            B1[i] = (xx - knot(i)) * 5.0f * B0[i] + (knot(i + 2) - xx) * 5.0f * B0[i + 1];
        }

        // degree 2: denom = 0.4 -> inv 2.5
        float B2[14];
        #pragma unroll
        for (int i = 0; i < 14; ++i) {
            B2[i] = (xx - knot(i)) * 2.5f * B1[i] + (knot(i + 3) - xx) * 2.5f * B1[i + 1];
        }

        // degree 3: denom = 0.6 -> inv 5/3
        #pragma unroll
        for (int i = 0; i < NB; ++i) {
            res[q][i] = (xx - knot(i)) * (5.0f / 3.0f) * B2[i] +
                        (knot(i + 4) - xx) * (5.0f / 3.0f) * B2[i + 1];
        }
    }

    #pragma unroll
    for (int b = 0; b < NB; ++b) {
        size_t off = ((size_t)row * NB + b) * cols + col;
        if constexpr (VEC == 4) {
            f32x4 o;
            o.x = res[0][b]; o.y = res[1][b]; o.z = res[2][b]; o.w = res[3][b];
            *reinterpret_cast<f32x4*>(out + off) = o;   // plain store: let L2/L3 absorb
        } else {
            out[off] = res[0][b];
        }
    }
}

extern "C" void kernel_launch(void* const* d_in, const int* in_sizes, int n_in,
                              void* d_out, int out_size, void* d_ws, size_t ws_size,
                              hipStream_t stream) {
    const float* x = (const float*)d_in[0];
    float* out = (float*)d_out;
    int cols = in_sizes[0] / NROWS;

    if ((cols & 3) == 0) {
        int nvec = cols / 4;
        int total = NROWS * nvec;
        int blocks = (total + 255) / 256;
        bspline_kernel<4><<<blocks, 256, 0, stream>>>(x, out, cols, nvec);
    } else {
        int total = NROWS * cols;
        int blocks = (total + 255) / 256;
        bspline_kernel<1><<<blocks, 256, 0, stream>>>(x, out, cols, cols);
    }
}

// Round 4
// 139.787 us; speedup vs baseline: 1.0437x; 1.0065x over previous
//
#include <hip/hip_runtime.h>

#define NROWS 5
#define NB 13          // output bases per row: 17 knots - 1 - k(=3)

// knot i value (uniform extended grid): g[i] = 0.2*i - 1.6
__device__ __forceinline__ float knot(int i) { return 0.2f * (float)i - 1.6f; }

__global__ __launch_bounds__(256) void bspline_kernel(const float* __restrict__ x,
                                                      float* __restrict__ out,
                                                      int cols) {
    int tid = blockIdx.x * blockDim.x + threadIdx.x;
    int total = NROWS * cols;
    if (tid >= total) return;
    int row = tid / cols;

    const float xx = x[tid];   // x is [NROWS][cols] row-major: flat index == tid

    // degree 0: indicator of [g[i], g[i+1])
    float B0[16];
    #pragma unroll
    for (int i = 0; i < 16; ++i) {
        B0[i] = (xx >= knot(i) && xx < knot(i + 1)) ? 1.0f : 0.0f;
    }

    // degree 1: denom = 0.2 -> inv 5
    float B1[15];
    #pragma unroll
    for (int i = 0; i < 15; ++i) {
        B1[i] = (xx - knot(i)) * 5.0f * B0[i] + (knot(i + 2) - xx) * 5.0f * B0[i + 1];
    }

    // degree 2: denom = 0.4 -> inv 2.5
    float B2[14];
    #pragma unroll
    for (int i = 0; i < 14; ++i) {
        B2[i] = (xx - knot(i)) * 2.5f * B1[i] + (knot(i + 3) - xx) * 2.5f * B1[i + 1];
    }

    // degree 3: denom = 0.6 -> inv 5/3
    float B3[NB];
    #pragma unroll
    for (int i = 0; i < NB; ++i) {
        B3[i] = (xx - knot(i)) * (5.0f / 3.0f) * B2[i] +
                (knot(i + 4) - xx) * (5.0f / 3.0f) * B2[i + 1];
    }

    // out[row][b][col]: offset = tid + row*12*cols + b*cols
    size_t base = (size_t)tid + (size_t)row * 12 * cols;
    #pragma unroll
    for (int b = 0; b < NB; ++b) {
        out[base + (size_t)b * cols] = B3[b];
    }
}

extern "C" void kernel_launch(void* const* d_in, const int* in_sizes, int n_in,
                              void* d_out, int out_size, void* d_ws, size_t ws_size,
                              hipStream_t stream) {
    const float* x = (const float*)d_in[0];
    float* out = (float*)d_out;
    int cols = in_sizes[0] / NROWS;

    int total = NROWS * cols;
    int blocks = (total + 255) / 256;
    bspline_kernel<<<blocks, 256, 0, stream>>>(x, out, cols);
}